// Round 2
// baseline (134.185 us; speedup 1.0000x reference)
//
#include <hip/hip_runtime.h>
#include <math.h>

#define NS 8192          // sampled points per part (24576/3)
#define NPTS 24576
#define YSPLIT 16
#define YTILE 512        // NS / YSPLIT
#define BX 256
#define XPT 4
#define XB (NS / (BX * XPT))   // 8
#define NSLAB (4 * XB)         // 32 slabs = (combo, xb)

// ws float layout:
// [0..3]    accum per combo (combo = part*2 + dir)   -- memset to 0
// [4]       global ticket (int)                      -- memset to 0
// [8..39]   slab tickets (32 ints)                   -- memset to 0
// [PARTIAL_OFF..] partial mins: [4 combos][YSPLIT][NS]
#define PARTIAL_OFF 131136

__device__ __forceinline__ void make_T12(const float* __restrict__ rq,
                                         const float* __restrict__ tra,
                                         int p, float* T) {
    float a = rq[p * 4 + 0], b = rq[p * 4 + 1];
    float c = rq[p * 4 + 2], d = rq[p * 4 + 3];
    float inv = rsqrtf(a * a + b * b + c * c + d * d);
    a *= inv; b *= inv; c *= inv; d *= inv;
    T[0]  = 1.f - 2.f * c * c - 2.f * d * d;
    T[1]  = 2.f * b * c - 2.f * a * d;
    T[2]  = 2.f * a * c + 2.f * b * d;
    T[3]  = tra[p * 3 + 0];
    T[4]  = 2.f * b * c + 2.f * a * d;
    T[5]  = 1.f - 2.f * b * b - 2.f * d * d;
    T[6]  = 2.f * c * d - 2.f * a * b;
    T[7]  = tra[p * 3 + 1];
    T[8]  = 2.f * b * d - 2.f * a * c;
    T[9]  = 2.f * a * b + 2.f * c * d;
    T[10] = 1.f - 2.f * b * b - 2.f * c * c;
    T[11] = tra[p * 3 + 2];
}

__global__ __launch_bounds__(BX) void chamfer_all(
    const float* __restrict__ cam, const float* __restrict__ cad,
    const float* __restrict__ rq,  const float* __restrict__ tr,
    const float* __restrict__ ja,  const float* __restrict__ pw,
    float* __restrict__ ws, float* __restrict__ out)
{
    int combo = blockIdx.y;
    int p   = combo >> 1;
    int dir = combo & 1;

    float T[12];
    make_T12(rq, tr, p, T);

    // ---- X setup: load raw points, transform if cad side ----
    int xbase = blockIdx.x * (BX * XPT) + threadIdx.x;
    const float* xsrc = (dir == 0 ? cad : cam) + p * NPTS * 3;
    float m0[XPT], m1[XPT], m2[XPT], s[XPT], dmin[XPT];
#pragma unroll
    for (int k = 0; k < XPT; ++k) {
        int i = xbase + k * BX;
        const float* sp = xsrc + i * 9;   // sample step 3 -> 9 floats
        float x = sp[0], y = sp[1], z = sp[2];
        if (dir == 0) {
            float tx = T[0] * x + T[1] * y + T[2]  * z + T[3];
            float ty = T[4] * x + T[5] * y + T[6]  * z + T[7];
            float tz = T[8] * x + T[9] * y + T[10] * z + T[11];
            x = tx; y = ty; z = tz;
        }
        m0[k] = -2.f * x; m1[k] = -2.f * y; m2[k] = -2.f * z;
        s[k]  = x * x + y * y + z * z;
        dmin[k] = 3.4e38f;
    }

    // ---- Y staging into LDS (transform if cad side) ----
    __shared__ float4 sy[YTILE];
    const float* ysrc = (dir == 0 ? cam : cad) + p * NPTS * 3;
    int ybase = blockIdx.z * YTILE;
#pragma unroll
    for (int t = 0; t < YTILE / BX; ++t) {
        int i = ybase + t * BX + threadIdx.x;
        const float* sp = ysrc + i * 9;
        float x = sp[0], y = sp[1], z = sp[2];
        if (dir == 1) {
            float tx = T[0] * x + T[1] * y + T[2]  * z + T[3];
            float ty = T[4] * x + T[5] * y + T[6]  * z + T[7];
            float tz = T[8] * x + T[9] * y + T[10] * z + T[11];
            x = tx; y = ty; z = tz;
        }
        sy[t * BX + threadIdx.x] = make_float4(x, y, z, x * x + y * y + z * z);
    }
    __syncthreads();

    // ---- inner loop: 3 FMA/pair + min3 per y-pair (s hoisted out) ----
#pragma unroll 4
    for (int j = 0; j < YTILE; j += 2) {
        float4 ya = sy[j];
        float4 yb = sy[j + 1];
#pragma unroll
        for (int k = 0; k < XPT; ++k) {
            float da = fmaf(m0[k], ya.x, ya.w);
            da = fmaf(m1[k], ya.y, da);
            da = fmaf(m2[k], ya.z, da);
            float db = fmaf(m0[k], yb.x, yb.w);
            db = fmaf(m1[k], yb.y, db);
            db = fmaf(m2[k], yb.z, db);
            dmin[k] = fminf(dmin[k], fminf(da, db));   // -> v_min3_f32
        }
    }

    // ---- partial writes (one z-slice of this slab) ----
    float* partial = ws + PARTIAL_OFF + combo * (YSPLIT * NS) + blockIdx.z * NS;
#pragma unroll
    for (int k = 0; k < XPT; ++k) {
        partial[xbase + k * BX] = s[k] + dmin[k];
    }

    // ---- slab ticket: last of 16 z-blocks reduces this slab ----
    __threadfence();   // release partials to device scope
    __shared__ int lastflag;
    int slab = combo * XB + blockIdx.x;
    if (threadIdx.x == 0) {
        int t = atomicAdd((int*)ws + 8 + slab, 1);
        lastflag = (t == YSPLIT - 1);
    }
    __syncthreads();
    if (!lastflag) return;

    // slab reduction: 1024 x's, min over 16 z-slices, sqrt, sum
    const float* pbase = ws + PARTIAL_OFF + combo * (YSPLIT * NS) + blockIdx.x * (BX * XPT);
    float dsum = 0.f;
#pragma unroll
    for (int k = 0; k < XPT; ++k) {
        int x = k * BX + threadIdx.x;
        float m = pbase[x];
#pragma unroll
        for (int z = 1; z < YSPLIT; ++z) m = fminf(m, pbase[z * NS + x]);
        dsum += sqrtf(fmaxf(m, 0.f));
    }
#pragma unroll
    for (int off = 32; off > 0; off >>= 1) dsum += __shfl_down(dsum, off, 64);

    __shared__ float sm[BX / 64];
    int wid = threadIdx.x >> 6;
    if ((threadIdx.x & 63) == 0) sm[wid] = dsum;
    __syncthreads();
    if (threadIdx.x != 0) return;

    float bs = sm[0] + sm[1] + sm[2] + sm[3];
    atomicAdd(&ws[combo], bs);
    __threadfence();
    int g = atomicAdd((int*)ws + 4, 1);
    if (g != NSLAB - 1) return;

    // ---- global-last: finalize (sole writer of out[], no shared lines) ----
    float a0 = atomicAdd(&ws[0], 0.f);   // coherent reads of accums
    float a1 = atomicAdd(&ws[1], 0.f);
    float a2 = atomicAdd(&ws[2], 0.f);
    float a3 = atomicAdd(&ws[3], 0.f);

    float TT[2][16];
    for (int q = 0; q < 2; ++q) {
        make_T12(rq, tr, q, TT[q]);
        TT[q][12] = 0.f; TT[q][13] = 0.f; TT[q][14] = 0.f; TT[q][15] = 1.f;
        for (int k = 0; k < 16; ++k) out[2 + q * 16 + k] = TT[q][k];
    }
    float ss = 0.f;
    for (int i = 0; i < 4; ++i) {
        for (int j = 0; j < 2; ++j) {
            float d0 = 0.f, d1 = 0.f;
            for (int k = 0; k < 4; ++k) {
                d0 += TT[0][i * 4 + k] * ja[0 * 8 + j * 4 + k];
                d1 += TT[1][i * 4 + k] * ja[1 * 8 + j * 4 + k];
            }
            float df = d0 - d1;
            ss += df * df;
        }
    }
    float ek = 1.f / (1.f + expf(5.f * sqrtf(ss)));
    out[1] = ek;

    float e0 = (a0 + a1) * (1.f / NS);
    float e1 = (a2 + a3) * (1.f / NS);
    out[0] = pw[0] * e0 + pw[1] * e1 + pw[2] * ek;
}

extern "C" void kernel_launch(void* const* d_in, const int* in_sizes, int n_in,
                              void* d_out, int out_size, void* d_ws, size_t ws_size,
                              hipStream_t stream) {
    const float* cam = (const float*)d_in[0];
    const float* cad = (const float*)d_in[1];
    const float* pw  = (const float*)d_in[2];
    const float* rq  = (const float*)d_in[3];
    const float* tr  = (const float*)d_in[4];
    const float* ja  = (const float*)d_in[5];
    float* out = (float*)d_out;
    float* ws  = (float*)d_ws;

    // zero accums + tickets (floats 0..39); graph-capturable memset node
    hipMemsetAsync(ws, 0, 160, stream);

    dim3 cg(XB, 4, YSPLIT);
    chamfer_all<<<cg, BX, 0, stream>>>(cam, cad, rq, tr, ja, pw, ws, out);
}

// Round 3
// 104.783 us; speedup vs baseline: 1.2806x; 1.2806x over previous
//
#include <hip/hip_runtime.h>
#include <math.h>

#define NS 8192          // sampled points per part (24576/3)
#define NPTS 24576
#define YSPLIT 64
#define YTILE 128        // NS / YSPLIT
#define BX 256
#define XPT 4
#define XB (NS / (BX * XPT))   // 8

// ws float layout:
// [0..3]    accum per combo (combo = part*2 + dir)
// [36]      e_kin
// [40]      ticket counter (int)
// [PARTIAL_OFF..] partial mins: [4 combos][YSPLIT][NS]  (8 MB)
#define PARTIAL_OFF 131136
#define RED_BLOCKS (4 * (NS / 64))   // 512: finalize ticket target

__device__ __forceinline__ void make_T12(const float* __restrict__ rq,
                                         const float* __restrict__ tra,
                                         int p, float* T) {
    float a = rq[p * 4 + 0], b = rq[p * 4 + 1];
    float c = rq[p * 4 + 2], d = rq[p * 4 + 3];
    float inv = rsqrtf(a * a + b * b + c * c + d * d);
    a *= inv; b *= inv; c *= inv; d *= inv;
    T[0]  = 1.f - 2.f * c * c - 2.f * d * d;
    T[1]  = 2.f * b * c - 2.f * a * d;
    T[2]  = 2.f * a * c + 2.f * b * d;
    T[3]  = tra[p * 3 + 0];
    T[4]  = 2.f * b * c + 2.f * a * d;
    T[5]  = 1.f - 2.f * b * b - 2.f * d * d;
    T[6]  = 2.f * c * d - 2.f * a * b;
    T[7]  = tra[p * 3 + 1];
    T[8]  = 2.f * b * d - 2.f * a * c;
    T[9]  = 2.f * a * b + 2.f * c * d;
    T[10] = 1.f - 2.f * b * b - 2.f * c * c;
    T[11] = tra[p * 3 + 2];
}

// Transform-on-the-fly chamfer partial mins. No fences, no tickets here:
// the kernel boundary provides device-wide visibility for the partials.
__global__ __launch_bounds__(BX) void chamfer_fused(
    const float* __restrict__ cam, const float* __restrict__ cad,
    const float* __restrict__ rq,  const float* __restrict__ tr,
    const float* __restrict__ ja,
    float* __restrict__ ws, float* __restrict__ out)
{
    int combo = blockIdx.y;
    int p   = combo >> 1;
    int dir = combo & 1;

    float T[12];
    make_T12(rq, tr, p, T);

    // housekeeping: one thread in the whole grid (reduce kernel runs after)
    if (blockIdx.x == 0 && blockIdx.y == 0 && blockIdx.z == 0 && threadIdx.x == 0) {
        float TT[2][16];
        for (int q = 0; q < 2; ++q) {
            make_T12(rq, tr, q, TT[q]);
            TT[q][12] = 0.f; TT[q][13] = 0.f; TT[q][14] = 0.f; TT[q][15] = 1.f;
            for (int k = 0; k < 16; ++k) out[2 + q * 16 + k] = TT[q][k];
        }
        float ss = 0.f;
        for (int i = 0; i < 4; ++i) {
            for (int j = 0; j < 2; ++j) {
                float d0 = 0.f, d1 = 0.f;
                for (int k = 0; k < 4; ++k) {
                    d0 += TT[0][i * 4 + k] * ja[0 * 8 + j * 4 + k];
                    d1 += TT[1][i * 4 + k] * ja[1 * 8 + j * 4 + k];
                }
                float df = d0 - d1;
                ss += df * df;
            }
        }
        float ek = 1.f / (1.f + expf(5.f * sqrtf(ss)));
        ws[36] = ek;
        out[1] = ek;
        ws[0] = 0.f; ws[1] = 0.f; ws[2] = 0.f; ws[3] = 0.f;
        *(int*)(ws + 40) = 0;
    }

    // ---- X setup: load raw points, transform if cad side ----
    int xbase = blockIdx.x * (BX * XPT) + threadIdx.x;
    const float* xsrc = (dir == 0 ? cad : cam) + p * NPTS * 3;
    float m0[XPT], m1[XPT], m2[XPT], s[XPT], dmin[XPT];
#pragma unroll
    for (int k = 0; k < XPT; ++k) {
        int i = xbase + k * BX;
        const float* sp = xsrc + i * 9;   // sample step 3 -> 9 floats
        float x = sp[0], y = sp[1], z = sp[2];
        if (dir == 0) {
            float tx = T[0] * x + T[1] * y + T[2]  * z + T[3];
            float ty = T[4] * x + T[5] * y + T[6]  * z + T[7];
            float tz = T[8] * x + T[9] * y + T[10] * z + T[11];
            x = tx; y = ty; z = tz;
        }
        m0[k] = -2.f * x; m1[k] = -2.f * y; m2[k] = -2.f * z;
        s[k]  = x * x + y * y + z * z;
        dmin[k] = 3.4e38f;
    }

    // ---- Y staging into LDS (transform if cad side); YTILE < BX ok ----
    __shared__ float4 sy[YTILE];
    const float* ysrc = (dir == 0 ? cam : cad) + p * NPTS * 3;
    int ybase = blockIdx.z * YTILE;
    for (int t = threadIdx.x; t < YTILE; t += BX) {
        const float* sp = ysrc + (ybase + t) * 9;
        float x = sp[0], y = sp[1], z = sp[2];
        if (dir == 1) {
            float tx = T[0] * x + T[1] * y + T[2]  * z + T[3];
            float ty = T[4] * x + T[5] * y + T[6]  * z + T[7];
            float tz = T[8] * x + T[9] * y + T[10] * z + T[11];
            x = tx; y = ty; z = tz;
        }
        sy[t] = make_float4(x, y, z, x * x + y * y + z * z);
    }
    __syncthreads();

    // ---- inner loop: 3 FMA/pair + min3 per y-pair (s hoisted out) ----
#pragma unroll 4
    for (int j = 0; j < YTILE; j += 2) {
        float4 ya = sy[j];
        float4 yb = sy[j + 1];
#pragma unroll
        for (int k = 0; k < XPT; ++k) {
            float da = fmaf(m0[k], ya.x, ya.w);
            da = fmaf(m1[k], ya.y, da);
            da = fmaf(m2[k], ya.z, da);
            float db = fmaf(m0[k], yb.x, yb.w);
            db = fmaf(m1[k], yb.y, db);
            db = fmaf(m2[k], yb.z, db);
            dmin[k] = fminf(dmin[k], fminf(da, db));   // -> v_min3_f32
        }
    }

    float* partial = ws + PARTIAL_OFF + combo * (YSPLIT * NS) + blockIdx.z * NS;
#pragma unroll
    for (int k = 0; k < XPT; ++k) {
        partial[xbase + k * BX] = s[k] + dmin[k];
    }
}

// Reduce + finalize. Block = 256 threads = 4 waves; each block covers 64 x's,
// each wave mins a 16-slice z-group (coalesced 64-wide rows), then wave 0
// combines across groups, sqrts, sums, atomicAdds. Last block finalizes.
__global__ __launch_bounds__(256) void reduce_final(
    float* __restrict__ ws, const float* __restrict__ pw,
    const float* __restrict__ rq, const float* __restrict__ tr,
    float* __restrict__ out)
{
    int combo = blockIdx.y;
    int lane = threadIdx.x & 63;
    int zg   = threadIdx.x >> 6;         // 0..3
    const float* p = ws + PARTIAL_OFF + combo * (YSPLIT * NS)
                   + blockIdx.x * 64 + lane;
    float m = 3.4e38f;
#pragma unroll
    for (int z = 0; z < YSPLIT / 4; ++z)
        m = fminf(m, p[(zg * (YSPLIT / 4) + z) * NS]);

    __shared__ float sm[4][64];
    sm[zg][lane] = m;
    __syncthreads();
    if (zg != 0) return;

    float mm = fminf(fminf(sm[0][lane], sm[1][lane]),
                     fminf(sm[2][lane], sm[3][lane]));
    float d = sqrtf(fmaxf(mm, 0.f));
#pragma unroll
    for (int off = 32; off > 0; off >>= 1) d += __shfl_down(d, off, 64);
    if (lane != 0) return;

    atomicAdd(&ws[combo], d);
    __threadfence();
    int t = atomicAdd((int*)(ws + 40), 1);
    if (t != RED_BLOCKS - 1) return;

    // ---- global-last block: finalize ----
    float a0 = atomicAdd(&ws[0], 0.f);   // coherent reads of accums
    float a1 = atomicAdd(&ws[1], 0.f);
    float a2 = atomicAdd(&ws[2], 0.f);
    float a3 = atomicAdd(&ws[3], 0.f);
    float e0 = (a0 + a1) * (1.f / NS);
    float e1 = (a2 + a3) * (1.f / NS);
    out[0] = pw[0] * e0 + pw[1] * e1 + pw[2] * ws[36];
}

extern "C" void kernel_launch(void* const* d_in, const int* in_sizes, int n_in,
                              void* d_out, int out_size, void* d_ws, size_t ws_size,
                              hipStream_t stream) {
    const float* cam = (const float*)d_in[0];
    const float* cad = (const float*)d_in[1];
    const float* pw  = (const float*)d_in[2];
    const float* rq  = (const float*)d_in[3];
    const float* tr  = (const float*)d_in[4];
    const float* ja  = (const float*)d_in[5];
    float* out = (float*)d_out;
    float* ws  = (float*)d_ws;

    dim3 cg(XB, 4, YSPLIT);
    chamfer_fused<<<cg, BX, 0, stream>>>(cam, cad, rq, tr, ja, ws, out);
    reduce_final<<<dim3(NS / 64, 4), 256, 0, stream>>>(ws, pw, rq, tr, out);
}

// Round 4
// 93.630 us; speedup vs baseline: 1.4331x; 1.1191x over previous
//
#include <hip/hip_runtime.h>
#include <math.h>

#define NS 8192          // sampled points per part (24576/3)
#define NPTS 24576
#define YSPLIT 16
#define YTILE 512        // NS / YSPLIT
#define BX 256
#define XPT 4
#define XB (NS / (BX * XPT))   // 8

// ws float layout:
// [0..3]    accum per combo (combo = part*2 + dir)
// [36]      e_kin
// [40]      ticket counter (int)
// [PARTIAL_OFF..] partial mins: [4 combos][YSPLIT][NS]  (2 MB)
#define PARTIAL_OFF 131136

__device__ __forceinline__ void make_T12(const float* __restrict__ rq,
                                         const float* __restrict__ tra,
                                         int p, float* T) {
    float a = rq[p * 4 + 0], b = rq[p * 4 + 1];
    float c = rq[p * 4 + 2], d = rq[p * 4 + 3];
    float inv = rsqrtf(a * a + b * b + c * c + d * d);
    a *= inv; b *= inv; c *= inv; d *= inv;
    T[0]  = 1.f - 2.f * c * c - 2.f * d * d;
    T[1]  = 2.f * b * c - 2.f * a * d;
    T[2]  = 2.f * a * c + 2.f * b * d;
    T[3]  = tra[p * 3 + 0];
    T[4]  = 2.f * b * c + 2.f * a * d;
    T[5]  = 1.f - 2.f * b * b - 2.f * d * d;
    T[6]  = 2.f * c * d - 2.f * a * b;
    T[7]  = tra[p * 3 + 1];
    T[8]  = 2.f * b * d - 2.f * a * c;
    T[9]  = 2.f * a * b + 2.f * c * d;
    T[10] = 1.f - 2.f * b * b - 2.f * c * c;
    T[11] = tra[p * 3 + 2];
}

// Transform-on-the-fly chamfer partial mins. No fences, no tickets here:
// the kernel boundary provides device-wide visibility for the partials.
// (Round-2 lesson: per-block __threadfence after the 268 MB ws poison
// forces L2 dirty-writeback storms — never fence in the hot kernel.)
__global__ __launch_bounds__(BX) void chamfer_fused(
    const float* __restrict__ cam, const float* __restrict__ cad,
    const float* __restrict__ rq,  const float* __restrict__ tr,
    const float* __restrict__ ja,
    float* __restrict__ ws, float* __restrict__ out)
{
    int combo = blockIdx.y;
    int p   = combo >> 1;
    int dir = combo & 1;

    float T[12];
    make_T12(rq, tr, p, T);

    // housekeeping: one thread in the whole grid (reduce kernel runs after)
    if (blockIdx.x == 0 && blockIdx.y == 0 && blockIdx.z == 0 && threadIdx.x == 0) {
        float TT[2][16];
        for (int q = 0; q < 2; ++q) {
            make_T12(rq, tr, q, TT[q]);
            TT[q][12] = 0.f; TT[q][13] = 0.f; TT[q][14] = 0.f; TT[q][15] = 1.f;
            for (int k = 0; k < 16; ++k) out[2 + q * 16 + k] = TT[q][k];
        }
        float ss = 0.f;
        for (int i = 0; i < 4; ++i) {
            for (int j = 0; j < 2; ++j) {
                float d0 = 0.f, d1 = 0.f;
                for (int k = 0; k < 4; ++k) {
                    d0 += TT[0][i * 4 + k] * ja[0 * 8 + j * 4 + k];
                    d1 += TT[1][i * 4 + k] * ja[1 * 8 + j * 4 + k];
                }
                float df = d0 - d1;
                ss += df * df;
            }
        }
        float ek = 1.f / (1.f + expf(5.f * sqrtf(ss)));
        ws[36] = ek;
        out[1] = ek;
        ws[0] = 0.f; ws[1] = 0.f; ws[2] = 0.f; ws[3] = 0.f;
        *(int*)(ws + 40) = 0;
    }

    // ---- X setup: load raw points, transform if cad side ----
    int xbase = blockIdx.x * (BX * XPT) + threadIdx.x;
    const float* xsrc = (dir == 0 ? cad : cam) + p * NPTS * 3;
    float m0[XPT], m1[XPT], m2[XPT], s[XPT], dmin[XPT];
#pragma unroll
    for (int k = 0; k < XPT; ++k) {
        int i = xbase + k * BX;
        const float* sp = xsrc + i * 9;   // sample step 3 -> 9 floats
        float x = sp[0], y = sp[1], z = sp[2];
        if (dir == 0) {
            float tx = T[0] * x + T[1] * y + T[2]  * z + T[3];
            float ty = T[4] * x + T[5] * y + T[6]  * z + T[7];
            float tz = T[8] * x + T[9] * y + T[10] * z + T[11];
            x = tx; y = ty; z = tz;
        }
        m0[k] = -2.f * x; m1[k] = -2.f * y; m2[k] = -2.f * z;
        s[k]  = x * x + y * y + z * z;
        dmin[k] = 3.4e38f;
    }

    // ---- Y staging into LDS (transform if cad side) ----
    __shared__ float4 sy[YTILE];
    const float* ysrc = (dir == 0 ? cam : cad) + p * NPTS * 3;
    int ybase = blockIdx.z * YTILE;
#pragma unroll
    for (int t = 0; t < YTILE / BX; ++t) {
        int i = ybase + t * BX + threadIdx.x;
        const float* sp = ysrc + i * 9;
        float x = sp[0], y = sp[1], z = sp[2];
        if (dir == 1) {
            float tx = T[0] * x + T[1] * y + T[2]  * z + T[3];
            float ty = T[4] * x + T[5] * y + T[6]  * z + T[7];
            float tz = T[8] * x + T[9] * y + T[10] * z + T[11];
            x = tx; y = ty; z = tz;
        }
        sy[t * BX + threadIdx.x] = make_float4(x, y, z, x * x + y * y + z * z);
    }
    __syncthreads();

    // ---- inner loop: 3 FMA/pair + min3 per y-pair (s hoisted out) ----
#pragma unroll 4
    for (int j = 0; j < YTILE; j += 2) {
        float4 ya = sy[j];
        float4 yb = sy[j + 1];
#pragma unroll
        for (int k = 0; k < XPT; ++k) {
            float da = fmaf(m0[k], ya.x, ya.w);
            da = fmaf(m1[k], ya.y, da);
            da = fmaf(m2[k], ya.z, da);
            float db = fmaf(m0[k], yb.x, yb.w);
            db = fmaf(m1[k], yb.y, db);
            db = fmaf(m2[k], yb.z, db);
            dmin[k] = fminf(dmin[k], fminf(da, db));   // -> v_min3_f32
        }
    }

    float* partial = ws + PARTIAL_OFF + combo * (YSPLIT * NS) + blockIdx.z * NS;
#pragma unroll
    for (int k = 0; k < XPT; ++k) {
        partial[xbase + k * BX] = s[k] + dmin[k];
    }
}

// Fused reduce + finalize: last block (atomic ticket) writes out[0].
__global__ __launch_bounds__(256) void reduce_final(
    float* __restrict__ ws, const float* __restrict__ pw,
    float* __restrict__ out)
{
    int combo = blockIdx.y;
    int x = blockIdx.x * 256 + threadIdx.x;
    const float* p = ws + PARTIAL_OFF + combo * (YSPLIT * NS) + x;
    float m = p[0];
#pragma unroll
    for (int ysi = 1; ysi < YSPLIT; ++ysi) m = fminf(m, p[ysi * NS]);
    float d = sqrtf(fmaxf(m, 0.f));
#pragma unroll
    for (int off = 32; off > 0; off >>= 1) d += __shfl_down(d, off, 64);

    __shared__ float sm[4];
    __shared__ bool last;
    int wid = threadIdx.x >> 6;
    if ((threadIdx.x & 63) == 0) sm[wid] = d;
    __syncthreads();
    if (threadIdx.x == 0) {
        float sum = sm[0] + sm[1] + sm[2] + sm[3];
        atomicAdd(&ws[combo], sum);
        __threadfence();
        int t = atomicAdd((int*)(ws + 40), 1);
        last = (t == 4 * (NS / 256) - 1);   // 127
    }
    __syncthreads();
    if (last && threadIdx.x == 0) {
        // atomic reads bypass any stale cache path (cross-XCD safe)
        float a0 = atomicAdd(&ws[0], 0.f);
        float a1 = atomicAdd(&ws[1], 0.f);
        float a2 = atomicAdd(&ws[2], 0.f);
        float a3 = atomicAdd(&ws[3], 0.f);
        float e0 = (a0 + a1) * (1.f / NS);
        float e1 = (a2 + a3) * (1.f / NS);
        out[0] = pw[0] * e0 + pw[1] * e1 + pw[2] * ws[36];
    }
}

extern "C" void kernel_launch(void* const* d_in, const int* in_sizes, int n_in,
                              void* d_out, int out_size, void* d_ws, size_t ws_size,
                              hipStream_t stream) {
    const float* cam = (const float*)d_in[0];
    const float* cad = (const float*)d_in[1];
    const float* pw  = (const float*)d_in[2];
    const float* rq  = (const float*)d_in[3];
    const float* tr  = (const float*)d_in[4];
    const float* ja  = (const float*)d_in[5];
    float* out = (float*)d_out;
    float* ws  = (float*)d_ws;

    dim3 cg(XB, 4, YSPLIT);
    chamfer_fused<<<cg, BX, 0, stream>>>(cam, cad, rq, tr, ja, ws, out);
    reduce_final<<<dim3(NS / 256, 4), 256, 0, stream>>>(ws, pw, out);
}

// Round 5
// 92.663 us; speedup vs baseline: 1.4481x; 1.0104x over previous
//
#include <hip/hip_runtime.h>
#include <math.h>

#define NS 8192          // sampled points per part (24576/3)
#define NPTS 24576
#define YSPLIT 16
#define YTILE 512        // NS / YSPLIT
#define BX 256
#define XPT 4
#define XB (NS / (BX * XPT))   // 8

typedef float v2f __attribute__((ext_vector_type(2)));

// ws float layout:
// [0..3]    accum per combo (combo = part*2 + dir)
// [36]      e_kin
// [40]      ticket counter (int)
// [PARTIAL_OFF..] partial mins: [4 combos][YSPLIT][NS]  (2 MB)
#define PARTIAL_OFF 131136

__device__ __forceinline__ void make_T12(const float* __restrict__ rq,
                                         const float* __restrict__ tra,
                                         int p, float* T) {
    float a = rq[p * 4 + 0], b = rq[p * 4 + 1];
    float c = rq[p * 4 + 2], d = rq[p * 4 + 3];
    float inv = rsqrtf(a * a + b * b + c * c + d * d);
    a *= inv; b *= inv; c *= inv; d *= inv;
    T[0]  = 1.f - 2.f * c * c - 2.f * d * d;
    T[1]  = 2.f * b * c - 2.f * a * d;
    T[2]  = 2.f * a * c + 2.f * b * d;
    T[3]  = tra[p * 3 + 0];
    T[4]  = 2.f * b * c + 2.f * a * d;
    T[5]  = 1.f - 2.f * b * b - 2.f * d * d;
    T[6]  = 2.f * c * d - 2.f * a * b;
    T[7]  = tra[p * 3 + 1];
    T[8]  = 2.f * b * d - 2.f * a * c;
    T[9]  = 2.f * a * b + 2.f * c * d;
    T[10] = 1.f - 2.f * b * b - 2.f * c * c;
    T[11] = tra[p * 3 + 2];
}

// Transform-on-the-fly chamfer partial mins. No fences, no tickets here:
// the kernel boundary provides device-wide visibility for the partials.
// (Round-2 lesson: per-block __threadfence after the 268 MB ws poison
// forces L2 dirty-writeback storms — never fence in the hot kernel.)
// Round-5 experiment: packed f32 inner loop via v_pk_fma_f32 (y-pairs).
__global__ __launch_bounds__(BX) void chamfer_fused(
    const float* __restrict__ cam, const float* __restrict__ cad,
    const float* __restrict__ rq,  const float* __restrict__ tr,
    const float* __restrict__ ja,
    float* __restrict__ ws, float* __restrict__ out)
{
    int combo = blockIdx.y;
    int p   = combo >> 1;
    int dir = combo & 1;

    float T[12];
    make_T12(rq, tr, p, T);

    // housekeeping: one thread in the whole grid (reduce kernel runs after)
    if (blockIdx.x == 0 && blockIdx.y == 0 && blockIdx.z == 0 && threadIdx.x == 0) {
        float TT[2][16];
        for (int q = 0; q < 2; ++q) {
            make_T12(rq, tr, q, TT[q]);
            TT[q][12] = 0.f; TT[q][13] = 0.f; TT[q][14] = 0.f; TT[q][15] = 1.f;
            for (int k = 0; k < 16; ++k) out[2 + q * 16 + k] = TT[q][k];
        }
        float ss = 0.f;
        for (int i = 0; i < 4; ++i) {
            for (int j = 0; j < 2; ++j) {
                float d0 = 0.f, d1 = 0.f;
                for (int k = 0; k < 4; ++k) {
                    d0 += TT[0][i * 4 + k] * ja[0 * 8 + j * 4 + k];
                    d1 += TT[1][i * 4 + k] * ja[1 * 8 + j * 4 + k];
                }
                float df = d0 - d1;
                ss += df * df;
            }
        }
        float ek = 1.f / (1.f + expf(5.f * sqrtf(ss)));
        ws[36] = ek;
        out[1] = ek;
        ws[0] = 0.f; ws[1] = 0.f; ws[2] = 0.f; ws[3] = 0.f;
        *(int*)(ws + 40) = 0;
    }

    // ---- X setup: load raw points, transform if cad side ----
    int xbase = blockIdx.x * (BX * XPT) + threadIdx.x;
    const float* xsrc = (dir == 0 ? cad : cam) + p * NPTS * 3;
    v2f m0p[XPT], m1p[XPT], m2p[XPT];
    float s[XPT], dmin[XPT];
#pragma unroll
    for (int k = 0; k < XPT; ++k) {
        int i = xbase + k * BX;
        const float* sp = xsrc + i * 9;   // sample step 3 -> 9 floats
        float x = sp[0], y = sp[1], z = sp[2];
        if (dir == 0) {
            float tx = T[0] * x + T[1] * y + T[2]  * z + T[3];
            float ty = T[4] * x + T[5] * y + T[6]  * z + T[7];
            float tz = T[8] * x + T[9] * y + T[10] * z + T[11];
            x = tx; y = ty; z = tz;
        }
        m0p[k] = (v2f){-2.f * x, -2.f * x};
        m1p[k] = (v2f){-2.f * y, -2.f * y};
        m2p[k] = (v2f){-2.f * z, -2.f * z};
        s[k]  = x * x + y * y + z * z;
        dmin[k] = 3.4e38f;
    }

    // ---- Y staging into LDS, pair-transposed SoA layout ----
    // pair block pr (8 floats): [x_e, x_o, y_e, y_o, z_e, z_o, w_e, w_o]
    __shared__ float syp[YTILE * 4];
    const float* ysrc = (dir == 0 ? cam : cad) + p * NPTS * 3;
    int ybase = blockIdx.z * YTILE;
#pragma unroll
    for (int t = 0; t < YTILE / BX; ++t) {
        int idx = t * BX + threadIdx.x;
        const float* sp = ysrc + (ybase + idx) * 9;
        float x = sp[0], y = sp[1], z = sp[2];
        if (dir == 1) {
            float tx = T[0] * x + T[1] * y + T[2]  * z + T[3];
            float ty = T[4] * x + T[5] * y + T[6]  * z + T[7];
            float tz = T[8] * x + T[9] * y + T[10] * z + T[11];
            x = tx; y = ty; z = tz;
        }
        int base = (idx >> 1) * 8 + (idx & 1);
        syp[base + 0] = x;
        syp[base + 2] = y;
        syp[base + 4] = z;
        syp[base + 6] = x * x + y * y + z * z;
    }
    __syncthreads();

    // ---- inner loop: per y-pair per x: 3 v_pk_fma_f32 + 1 v_min3_f32 ----
    const float4* syp4 = (const float4*)syp;
#pragma unroll 4
    for (int j = 0; j < YTILE / 2; ++j) {
        float4 A = syp4[j * 2];       // {x_e, x_o, y_e, y_o}
        float4 B = syp4[j * 2 + 1];   // {z_e, z_o, w_e, w_o}
        v2f px = {A.x, A.y};
        v2f py = {A.z, A.w};
        v2f pz = {B.x, B.y};
        v2f pw = {B.z, B.w};
#pragma unroll
        for (int k = 0; k < XPT; ++k) {
            v2f d;
            asm("v_pk_fma_f32 %0, %1, %2, %3"
                : "=v"(d) : "v"(m0p[k]), "v"(px), "v"(pw));
            asm("v_pk_fma_f32 %0, %1, %2, %0"
                : "+v"(d) : "v"(m1p[k]), "v"(py));
            asm("v_pk_fma_f32 %0, %1, %2, %0"
                : "+v"(d) : "v"(m2p[k]), "v"(pz));
            dmin[k] = fminf(fminf(d.x, d.y), dmin[k]);   // -> v_min3_f32
        }
    }

    float* partial = ws + PARTIAL_OFF + combo * (YSPLIT * NS) + blockIdx.z * NS;
#pragma unroll
    for (int k = 0; k < XPT; ++k) {
        partial[xbase + k * BX] = s[k] + dmin[k];
    }
}

// Fused reduce + finalize: last block (atomic ticket) writes out[0].
__global__ __launch_bounds__(256) void reduce_final(
    float* __restrict__ ws, const float* __restrict__ pw,
    float* __restrict__ out)
{
    int combo = blockIdx.y;
    int x = blockIdx.x * 256 + threadIdx.x;
    const float* p = ws + PARTIAL_OFF + combo * (YSPLIT * NS) + x;
    float m = p[0];
#pragma unroll
    for (int ysi = 1; ysi < YSPLIT; ++ysi) m = fminf(m, p[ysi * NS]);
    float d = sqrtf(fmaxf(m, 0.f));
#pragma unroll
    for (int off = 32; off > 0; off >>= 1) d += __shfl_down(d, off, 64);

    __shared__ float sm[4];
    __shared__ bool last;
    int wid = threadIdx.x >> 6;
    if ((threadIdx.x & 63) == 0) sm[wid] = d;
    __syncthreads();
    if (threadIdx.x == 0) {
        float sum = sm[0] + sm[1] + sm[2] + sm[3];
        atomicAdd(&ws[combo], sum);
        __threadfence();
        int t = atomicAdd((int*)(ws + 40), 1);
        last = (t == 4 * (NS / 256) - 1);   // 127
    }
    __syncthreads();
    if (last && threadIdx.x == 0) {
        // atomic reads bypass any stale cache path (cross-XCD safe)
        float a0 = atomicAdd(&ws[0], 0.f);
        float a1 = atomicAdd(&ws[1], 0.f);
        float a2 = atomicAdd(&ws[2], 0.f);
        float a3 = atomicAdd(&ws[3], 0.f);
        float e0 = (a0 + a1) * (1.f / NS);
        float e1 = (a2 + a3) * (1.f / NS);
        out[0] = pw[0] * e0 + pw[1] * e1 + pw[2] * ws[36];
    }
}

extern "C" void kernel_launch(void* const* d_in, const int* in_sizes, int n_in,
                              void* d_out, int out_size, void* d_ws, size_t ws_size,
                              hipStream_t stream) {
    const float* cam = (const float*)d_in[0];
    const float* cad = (const float*)d_in[1];
    const float* pw  = (const float*)d_in[2];
    const float* rq  = (const float*)d_in[3];
    const float* tr  = (const float*)d_in[4];
    const float* ja  = (const float*)d_in[5];
    float* out = (float*)d_out;
    float* ws  = (float*)d_ws;

    dim3 cg(XB, 4, YSPLIT);
    chamfer_fused<<<cg, BX, 0, stream>>>(cam, cad, rq, tr, ja, ws, out);
    reduce_final<<<dim3(NS / 256, 4), 256, 0, stream>>>(ws, pw, out);
}